// Round 1
// baseline (375.468 us; speedup 1.0000x reference)
//
#include <hip/hip_runtime.h>

#define TLF_N     500000
#define TLF_ITERS 10
#define TLF_GRID  3125   // 3125 blocks * 10 iters * 16 rows = 500000

typedef short bf16x8 __attribute__((ext_vector_type(8)));
typedef float f32x4  __attribute__((ext_vector_type(4)));

__device__ __forceinline__ short f2bf(float f) {
  union { float f; unsigned u; } v; v.f = f;
  return (short)((v.u + 0x7fffu + ((v.u >> 16) & 1u)) >> 16);  // RNE
}

__device__ __forceinline__ bf16x8 pack8(float a0, float a1, float a2, float a3,
                                        float a4, float a5, float a6, float a7) {
  bf16x8 r;
  r[0] = f2bf(a0); r[1] = f2bf(a1); r[2] = f2bf(a2); r[3] = f2bf(a3);
  r[4] = f2bf(a4); r[5] = f2bf(a5); r[6] = f2bf(a6); r[7] = f2bf(a7);
  return r;
}

__device__ __forceinline__ bf16x8 frag_from_lds(const float* row, int kb) {
  const float4 a0 = *reinterpret_cast<const float4*>(row + kb);
  const float4 a1 = *reinterpret_cast<const float4*>(row + kb + 4);
  return pack8(a0.x, a0.y, a0.z, a0.w, a1.x, a1.y, a1.z, a1.w);
}

__launch_bounds__(256)
__global__ void tlf_kernel(const float* __restrict__ tokens,
                           const float* __restrict__ amask,
                           const float* __restrict__ type_emb,
                           const float* __restrict__ ipw,
                           const float* __restrict__ ipb,
                           const float* __restrict__ opw,
                           const float* __restrict__ opb,
                           const float* __restrict__ l1sv,
                           const float* __restrict__ l1bv,
                           const float* __restrict__ w1,
                           const float* __restrict__ b1v,
                           const float* __restrict__ w2,
                           const float* __restrict__ b2v,
                           const float* __restrict__ l2sv,
                           const float* __restrict__ l2bv,
                           const float* __restrict__ gwv,
                           const float* __restrict__ gbv,
                           float* __restrict__ out) {
  // per-wave private LDS scratch (stride 36 floats = 144B, 16B-aligned rows)
  __shared__ float xb[4][16][36];  // x = tokens + type_emb (token-row major)
  __shared__ float cb[4][16][36];  // conversion buffer: ctx -> x1 -> h

  const int tid = threadIdx.x;
  const int w   = tid >> 6;        // wave 0..3
  const int l   = tid & 63;        // lane
  const int g   = l >> 4;          // 0..3: data-row subgroup / k-block
  const int c   = l & 15;          // 0..15: column lane
  const int kb  = g << 3;          // k offset for A/B frags
  const int lr  = l >> 2;          // token-row this lane loads (0..15)
  const int e0  = (l & 3) << 3;    // channel offset this lane loads

  // ---- preload weights as B-frags (B[k][col] = W[col_f][k_e]) ----
  bf16x8 Bin[6], Bo[2], Bw1[2], Bw2[2];
  float  bq[6], bo[2], bb1[2], bb2[2];
  float  l1s[2], l1b[2], l2s[2], l2b[2], gw[2];
  #pragma unroll
  for (int t = 0; t < 6; ++t) {
    const float* p = ipw + (t * 16 + c) * 32 + kb;
    Bin[t] = pack8(p[0], p[1], p[2], p[3], p[4], p[5], p[6], p[7]);
    bq[t]  = ipb[t * 16 + c];
  }
  #pragma unroll
  for (int t = 0; t < 2; ++t) {
    const int f = t * 16 + c;
    const float* p0 = opw + f * 32 + kb;
    const float* p1 = w1  + f * 32 + kb;
    const float* p2 = w2  + f * 32 + kb;
    Bo[t]  = pack8(p0[0], p0[1], p0[2], p0[3], p0[4], p0[5], p0[6], p0[7]);
    Bw1[t] = pack8(p1[0], p1[1], p1[2], p1[3], p1[4], p1[5], p1[6], p1[7]);
    Bw2[t] = pack8(p2[0], p2[1], p2[2], p2[3], p2[4], p2[5], p2[6], p2[7]);
    bo[t]  = opb[f];  bb1[t] = b1v[f];  bb2[t] = b2v[f];
    l1s[t] = l1sv[f]; l1b[t] = l1bv[f];
    l2s[t] = l2sv[f]; l2b[t] = l2bv[f];
    gw[t]  = gwv[f];
  }
  const float gb = gbv[0];

  float te[8];
  {
    const float* p = type_emb + ((lr & 3) << 5) + e0;  // m = lr&3 (tr base % 4 == 0)
    #pragma unroll
    for (int j = 0; j < 8; ++j) te[j] = p[j];
  }

  for (int it = 0; it < TLF_ITERS; ++it) {
    const int tile = blockIdx.x * TLF_ITERS + it;
    const int dr0  = tile * 16 + (w << 2);   // first data row of this wave

    // ---- P1: load x = tokens + type_emb -> LDS ----
    {
      const float* tp = tokens + ((size_t)dr0 * 4 + lr) * 32 + e0;
      float4 v0 = *reinterpret_cast<const float4*>(tp);
      float4 v1 = *reinterpret_cast<const float4*>(tp + 4);
      v0.x += te[0]; v0.y += te[1]; v0.z += te[2]; v0.w += te[3];
      v1.x += te[4]; v1.y += te[5]; v1.z += te[6]; v1.w += te[7];
      *reinterpret_cast<float4*>(&xb[w][lr][e0])     = v0;
      *reinterpret_cast<float4*>(&xb[w][lr][e0 + 4]) = v1;
    }
    float mkv[4];
    {
      const float4 mk = *reinterpret_cast<const float4*>(amask + (size_t)(dr0 + g) * 4);
      mkv[0] = mk.x; mkv[1] = mk.y; mkv[2] = mk.z; mkv[3] = mk.w;
    }
    __syncthreads();

    // ---- P2: qkv = x @ in_proj_w^T + b (6 MFMA tiles of 16 f-cols) ----
    const bf16x8 ax = frag_from_lds(&xb[w][c][0], kb);
    f32x4 acc[6];
    #pragma unroll
    for (int t = 0; t < 6; ++t) {
      f32x4 z = {0.f, 0.f, 0.f, 0.f};
      acc[t] = __builtin_amdgcn_mfma_f32_16x16x32_bf16(ax, Bin[t], z, 0, 0, 0);
      #pragma unroll
      for (int m = 0; m < 4; ++m) acc[t][m] += bq[t];
    }
    // residual copy of x in C layout (rows 4g+m, cols c / 16+c)
    float xc[4][2];
    #pragma unroll
    for (int m = 0; m < 4; ++m) {
      xc[m][0] = xb[w][(g << 2) + m][c];
      xc[m][1] = xb[w][(g << 2) + m][16 + c];
    }

    // ---- P3: attention (in-register; 8-lane head groups) ----
    const float isq = 0.3535533905932738f;  // 1/sqrt(HD)
    #pragma unroll
    for (int t = 0; t < 2; ++t)
      #pragma unroll
      for (int m = 0; m < 4; ++m) acc[t][m] *= isq;  // prescale q
    float kbias[4];
    #pragma unroll
    for (int mp = 0; mp < 4; ++mp) kbias[mp] = (mkv[mp] > 0.f) ? 0.f : -1e9f;

    float ctxv[2][4];
    #pragma unroll
    for (int t = 0; t < 2; ++t) {  // tile t: channels 16t+c, head = 2t + (c>>3)
      float att[4][4];
      #pragma unroll
      for (int m = 0; m < 4; ++m) {
        #pragma unroll
        for (int mp = 0; mp < 4; ++mp) {
          float p = acc[t][m] * acc[2 + t][mp];     // q[m]*k[mp] partial (this lane's ch)
          p += __shfl_xor(p, 1, 64);
          p += __shfl_xor(p, 2, 64);
          p += __shfl_xor(p, 4, 64);                // sum over the 8 head channels
          att[m][mp] = p + kbias[mp];
        }
      }
      #pragma unroll
      for (int m = 0; m < 4; ++m) {
        const float mx  = fmaxf(fmaxf(att[m][0], att[m][1]), fmaxf(att[m][2], att[m][3]));
        const float ex0 = __expf(att[m][0] - mx);
        const float ex1 = __expf(att[m][1] - mx);
        const float ex2 = __expf(att[m][2] - mx);
        const float ex3 = __expf(att[m][3] - mx);
        const float inv = 1.f / (ex0 + ex1 + ex2 + ex3);
        ctxv[t][m] = (ex0 * acc[4 + t][0] + ex1 * acc[4 + t][1] +
                      ex2 * acc[4 + t][2] + ex3 * acc[4 + t][3]) * inv;
      }
    }

    // ---- P4: out_proj + residual + LN1 ----
    #pragma unroll
    for (int m = 0; m < 4; ++m) {
      cb[w][(g << 2) + m][c]      = ctxv[0][m];
      cb[w][(g << 2) + m][16 + c] = ctxv[1][m];
    }
    __syncthreads();
    const bf16x8 actx = frag_from_lds(&cb[w][c][0], kb);
    float y[4][2];
    #pragma unroll
    for (int t = 0; t < 2; ++t) {
      f32x4 z = {0.f, 0.f, 0.f, 0.f};
      f32x4 ao = __builtin_amdgcn_mfma_f32_16x16x32_bf16(actx, Bo[t], z, 0, 0, 0);
      #pragma unroll
      for (int m = 0; m < 4; ++m) y[m][t] = xc[m][t] + ao[m] + bo[t];
    }
    float x1v[4][2];
    #pragma unroll
    for (int m = 0; m < 4; ++m) {
      float s  = y[m][0] + y[m][1];
      float ss = y[m][0] * y[m][0] + y[m][1] * y[m][1];
      #pragma unroll
      for (int mm = 1; mm <= 8; mm <<= 1) {
        s  += __shfl_xor(s, mm, 64);
        ss += __shfl_xor(ss, mm, 64);
      }
      const float mu  = s * 0.03125f;
      const float var = ss * 0.03125f - mu * mu;
      const float rs  = rsqrtf(var + 1e-5f);
      x1v[m][0] = (y[m][0] - mu) * rs * l1s[0] + l1b[0];
      x1v[m][1] = (y[m][1] - mu) * rs * l1s[1] + l1b[1];
    }

    // ---- P5: FFN layer 1 (relu) ----
    __syncthreads();
    #pragma unroll
    for (int m = 0; m < 4; ++m) {
      cb[w][(g << 2) + m][c]      = x1v[m][0];
      cb[w][(g << 2) + m][16 + c] = x1v[m][1];
    }
    __syncthreads();
    const bf16x8 ax1 = frag_from_lds(&cb[w][c][0], kb);
    float hv[4][2];
    #pragma unroll
    for (int t = 0; t < 2; ++t) {
      f32x4 z = {0.f, 0.f, 0.f, 0.f};
      f32x4 ah = __builtin_amdgcn_mfma_f32_16x16x32_bf16(ax1, Bw1[t], z, 0, 0, 0);
      #pragma unroll
      for (int m = 0; m < 4; ++m) hv[m][t] = fmaxf(ah[m] + bb1[t], 0.f);
    }

    // ---- P6: FFN layer 2 + residual + LN2 ----
    __syncthreads();
    #pragma unroll
    for (int m = 0; m < 4; ++m) {
      cb[w][(g << 2) + m][c]      = hv[m][0];
      cb[w][(g << 2) + m][16 + c] = hv[m][1];
    }
    __syncthreads();
    const bf16x8 ah2 = frag_from_lds(&cb[w][c][0], kb);
    f32x4 f0, f1;
    {
      f32x4 z = {0.f, 0.f, 0.f, 0.f};
      f0 = __builtin_amdgcn_mfma_f32_16x16x32_bf16(ah2, Bw2[0], z, 0, 0, 0);
    }
    {
      f32x4 z = {0.f, 0.f, 0.f, 0.f};
      f1 = __builtin_amdgcn_mfma_f32_16x16x32_bf16(ah2, Bw2[1], z, 0, 0, 0);
    }
    float x2v[4][2];
    #pragma unroll
    for (int m = 0; m < 4; ++m) {
      const float y0 = x1v[m][0] + f0[m] + bb2[0];
      const float y1 = x1v[m][1] + f1[m] + bb2[1];
      float s  = y0 + y1;
      float ss = y0 * y0 + y1 * y1;
      #pragma unroll
      for (int mm = 1; mm <= 8; mm <<= 1) {
        s  += __shfl_xor(s, mm, 64);
        ss += __shfl_xor(ss, mm, 64);
      }
      const float mu  = s * 0.03125f;
      const float var = ss * 0.03125f - mu * mu;
      const float rs  = rsqrtf(var + 1e-5f);
      x2v[m][0] = (y0 - mu) * rs * l2s[0] + l2b[0];
      x2v[m][1] = (y1 - mu) * rs * l2s[1] + l2b[1];
    }

    // ---- P7: gated masked-softmax pooling ----
    float gp[4];
    #pragma unroll
    for (int m = 0; m < 4; ++m) {
      gp[m] = x2v[m][0] * gw[0] + x2v[m][1] * gw[1];
      #pragma unroll
      for (int mm = 1; mm <= 8; mm <<= 1) gp[m] += __shfl_xor(gp[m], mm, 64);
    }
    float lg[4];
    #pragma unroll
    for (int m = 0; m < 4; ++m) lg[m] = (mkv[m] > 0.f) ? (gp[m] + gb) : -1e9f;
    const float mx = fmaxf(fmaxf(lg[0], lg[1]), fmaxf(lg[2], lg[3]));
    float em[4], se = 0.f, sem = 0.f;
    #pragma unroll
    for (int m = 0; m < 4; ++m) {
      const float e = __expf(lg[m] - mx);
      se += e;
      em[m] = e * mkv[m];
      sem += em[m];
    }
    // weights = (e*mask/se) / (sum(e*mask)/se + 1e-8) = em / (sem + 1e-8*se)
    const float invd = 1.f / (sem + 1e-8f * se);
    float wt[4];
    #pragma unroll
    for (int m = 0; m < 4; ++m) wt[m] = em[m] * invd;
    float fused0 = 0.f, fused1 = 0.f;
    #pragma unroll
    for (int m = 0; m < 4; ++m) {
      fused0 += x2v[m][0] * wt[m];
      fused1 += x2v[m][1] * wt[m];
    }

    // ---- stores ----
    float* orow = out + (size_t)(dr0 + g) * 32;
    orow[c]      = fused0;
    orow[16 + c] = fused1;
    if (c == 0) {
      *reinterpret_cast<float4*>(out + (size_t)TLF_N * 32 + (size_t)(dr0 + g) * 4) =
          make_float4(wt[0], wt[1], wt[2], wt[3]);
    }
    __syncthreads();  // protect xb/cb before next iteration's writes
  }
}

extern "C" void kernel_launch(void* const* d_in, const int* in_sizes, int n_in,
                              void* d_out, int out_size, void* d_ws, size_t ws_size,
                              hipStream_t stream) {
  tlf_kernel<<<TLF_GRID, 256, 0, stream>>>(
      (const float*)d_in[0],  (const float*)d_in[1],  (const float*)d_in[2],
      (const float*)d_in[3],  (const float*)d_in[4],  (const float*)d_in[5],
      (const float*)d_in[6],  (const float*)d_in[7],  (const float*)d_in[8],
      (const float*)d_in[9],  (const float*)d_in[10], (const float*)d_in[11],
      (const float*)d_in[12], (const float*)d_in[13], (const float*)d_in[14],
      (const float*)d_in[15], (const float*)d_in[16], (float*)d_out);
}

// Round 2
// 296.326 us; speedup vs baseline: 1.2671x; 1.2671x over previous
//
#include <hip/hip_runtime.h>

#define TLF_N     500000
#define TLF_ITERS 5
#define TLF_GRID  3125   // 3125 blocks * 5 iters * 32 rows = 500000

typedef short bf16x8 __attribute__((ext_vector_type(8)));
typedef float f32x4  __attribute__((ext_vector_type(4)));
typedef int   i32x4  __attribute__((ext_vector_type(4)));

// wave-private LDS ordering fence: waits all DS ops, blocks compiler reordering
#define LDSFENCE asm volatile("s_waitcnt lgkmcnt(0)" ::: "memory")

__device__ __forceinline__ int cvt_pk(float lo, float hi) {
  int r;
  asm("v_cvt_pk_bf16_f32 %0, %1, %2" : "=v"(r) : "v"(lo), "v"(hi));
  return r;
}

__device__ __forceinline__ bf16x8 pack8f(float a0, float a1, float a2, float a3,
                                         float a4, float a5, float a6, float a7) {
  i32x4 r;
  r[0] = cvt_pk(a0, a1); r[1] = cvt_pk(a2, a3);
  r[2] = cvt_pk(a4, a5); r[3] = cvt_pk(a6, a7);
  return __builtin_bit_cast(bf16x8, r);
}

template<int CTRL>
__device__ __forceinline__ float dppf(float x) {
  return __builtin_bit_cast(float, __builtin_amdgcn_update_dpp(
      0, __builtin_bit_cast(int, x), CTRL, 0xF, 0xF, true));
}

// sum over aligned 8-lane groups (quad_perm xor1, xor2, half-mirror) — pure VALU
__device__ __forceinline__ float red8(float x) {
  x += dppf<0xB1>(x);
  x += dppf<0x4E>(x);
  x += dppf<0x141>(x);
  return x;
}
// sum over aligned 16-lane rows (xor1, xor2, ror4, ror8) — pure VALU
__device__ __forceinline__ float red16(float x) {
  x += dppf<0xB1>(x);
  x += dppf<0x4E>(x);
  x += dppf<0x124>(x);
  x += dppf<0x128>(x);
  return x;
}

__device__ __forceinline__ i32x4 packrow(const float* p, float s) {
  i32x4 r;
  r[0] = cvt_pk(p[0]*s, p[1]*s); r[1] = cvt_pk(p[2]*s, p[3]*s);
  r[2] = cvt_pk(p[4]*s, p[5]*s); r[3] = cvt_pk(p[6]*s, p[7]*s);
  return r;
}

// weight-frag read from LDS with LICM-defeating opaque index
__device__ __forceinline__ bf16x8 ldfrag(const int* wl, int slot) {
  int idx = slot * 4;
  asm volatile("" : "+v"(idx));
  return __builtin_bit_cast(bf16x8, *reinterpret_cast<const i32x4*>(wl + idx));
}

// A-frag (bf16) from a C-layout LDS row
__device__ __forceinline__ bf16x8 fragA(const float* row, int kb) {
  const float4 a = *reinterpret_cast<const float4*>(row + kb);
  const float4 b = *reinterpret_cast<const float4*>(row + kb + 4);
  return pack8f(a.x, a.y, a.z, a.w, b.x, b.y, b.z, b.w);
}

__launch_bounds__(256, 4)
__global__ void tlf_kernel(const float* __restrict__ tokens,
                           const float* __restrict__ amask,
                           const float* __restrict__ type_emb,
                           const float* __restrict__ ipw,
                           const float* __restrict__ ipb,
                           const float* __restrict__ opw,
                           const float* __restrict__ opb,
                           const float* __restrict__ l1sv,
                           const float* __restrict__ l1bv,
                           const float* __restrict__ w1,
                           const float* __restrict__ b1v,
                           const float* __restrict__ w2,
                           const float* __restrict__ b2v,
                           const float* __restrict__ l2sv,
                           const float* __restrict__ l2bv,
                           const float* __restrict__ gwv,
                           const float* __restrict__ gbv,
                           float* __restrict__ out) {
  // weight frags, shared per block: [lane][slot*4 dwords], stride 60 dwords (2-way banks max)
  __shared__ int   wfr[64 * 60];
  // per-(wave,subtile) C->A transpose buffer, stride 36 floats
  __shared__ float cb[4][2][16][36];

  const int tid = threadIdx.x;
  const int w   = tid >> 6;
  const int l   = tid & 63;
  const int g   = l >> 4;          // 16-lane row group = data-row slot / k-block
  const int c   = l & 15;          // column lane
  const int kb  = g << 3;

  const float qs = 0.3535533905932738f;  // 1/sqrt(HD)

  float bq[6], bo[2], bb1[2], bb2[2];
  float l1s[2], l1b[2], l2s[2], l2b[2], gw[2];

  int* wl = &wfr[l * 60];
  // slots 0..5: in_proj tiles (q tiles pre-scaled by 1/sqrt(HD))
  #pragma unroll
  for (int t = 0; t < 6; ++t) {
    const float s = (t < 2) ? qs : 1.0f;
    *reinterpret_cast<i32x4*>(wl + t * 4) = packrow(ipw + (t * 16 + c) * 32 + kb, s);
    bq[t] = ipb[t * 16 + c] * s;
  }
  // slots 6,7: out_proj; 8,9: w1; 10,11: w2
  #pragma unroll
  for (int t = 0; t < 2; ++t) {
    const int f = t * 16 + c;
    *reinterpret_cast<i32x4*>(wl + (6 + t) * 4)  = packrow(opw + f * 32 + kb, 1.f);
    *reinterpret_cast<i32x4*>(wl + (8 + t) * 4)  = packrow(w1  + f * 32 + kb, 1.f);
    *reinterpret_cast<i32x4*>(wl + (10 + t) * 4) = packrow(w2  + f * 32 + kb, 1.f);
    bo[t]  = opb[f];  bb1[t] = b1v[f]; bb2[t] = b2v[f];
    l1s[t] = l1sv[f]; l1b[t] = l1bv[f];
    l2s[t] = l2sv[f]; l2b[t] = l2bv[f];
    gw[t]  = gwv[f];
  }
  // slots 12,13: identity tiles (A-layout -> C-layout converter)
  #pragma unroll
  for (int t = 0; t < 2; ++t) {
    i32x4 fb;
    #pragma unroll
    for (int q = 0; q < 4; ++q) {
      const int lo = (kb + 2 * q     == t * 16 + c) ? 0x3F80 : 0;
      const int hi = (kb + 2 * q + 1 == t * 16 + c) ? 0x3F80 : 0;
      fb[q] = lo | (hi << 16);
    }
    *reinterpret_cast<i32x4*>(wl + (12 + t) * 4) = fb;
  }
  const float gb = gbv[0];

  float teA[8];
  {
    const float* tp = type_emb + ((c & 3) << 5) + kb;  // m = c&3, channels kb..kb+7
    #pragma unroll
    for (int j = 0; j < 8; ++j) teA[j] = tp[j];
  }
  // each wave wrote (identical) frags itself; in-order DS => its reads see them. No barrier.

  for (int it = 0; it < TLF_ITERS; ++it) {
    const int tile = blockIdx.x * TLF_ITERS + it;
    int dr[2];
    dr[0] = tile * 32 + w * 8;
    dr[1] = dr[0] + 4;

    // ---- P1: x A-frags straight from global (+type_emb), mask ----
    bf16x8 ax[2];
    float  mskv[2][4], kb8[2][4];
    #pragma unroll
    for (int u = 0; u < 2; ++u) {
      const float* tp = tokens + ((size_t)dr[u] * 4 + c) * 32 + kb;
      const float4 v0 = *reinterpret_cast<const float4*>(tp);
      const float4 v1 = *reinterpret_cast<const float4*>(tp + 4);
      ax[u] = pack8f(v0.x + teA[0], v0.y + teA[1], v0.z + teA[2], v0.w + teA[3],
                     v1.x + teA[4], v1.y + teA[5], v1.z + teA[6], v1.w + teA[7]);
      const float4 mk = *reinterpret_cast<const float4*>(amask + (size_t)(dr[u] + g) * 4);
      mskv[u][0] = mk.x; mskv[u][1] = mk.y; mskv[u][2] = mk.z; mskv[u][3] = mk.w;
      #pragma unroll
      for (int m = 0; m < 4; ++m)
        kb8[u][m] = (mskv[u][m] > 0.f) ? 0.f : -1.25e8f;  // summed over 8 lanes -> -1e9
    }

    // ---- xc: x in C layout via identity MFMAs (MFMA pipe is idle anyway) ----
    f32x4 xcT[2][2];
    #pragma unroll
    for (int u = 0; u < 2; ++u) {
      #pragma unroll
      for (int t = 0; t < 2; ++t) {
        const bf16x8 bid = ldfrag(wl, 12 + t);
        f32x4 z = {0.f, 0.f, 0.f, 0.f};
        xcT[u][t] = __builtin_amdgcn_mfma_f32_16x16x32_bf16(ax[u], bid, z, 0, 0, 0);
      }
    }

    // ---- P2: qkv (bias seeded via MFMA C-in) ----
    f32x4 acc[2][6];
    #pragma unroll
    for (int u = 0; u < 2; ++u) {
      #pragma unroll
      for (int t = 0; t < 6; ++t) {
        const bf16x8 bw = ldfrag(wl, t);
        f32x4 bs;
        #pragma unroll
        for (int m = 0; m < 4; ++m) bs[m] = bq[t];
        acc[u][t] = __builtin_amdgcn_mfma_f32_16x16x32_bf16(ax[u], bw, bs, 0, 0, 0);
      }
    }

    // ---- P3: attention, fully in-register (8-lane head groups, DPP reduce) ----
    float ctxv[2][2][4];
    #pragma unroll
    for (int u = 0; u < 2; ++u) {
      #pragma unroll
      for (int t = 0; t < 2; ++t) {
        float att[4][4];
        #pragma unroll
        for (int m = 0; m < 4; ++m) {
          #pragma unroll
          for (int mp = 0; mp < 4; ++mp) {
            const float p = fmaf(acc[u][t][m], acc[u][2 + t][mp], kb8[u][mp]);
            att[m][mp] = red8(p);
          }
        }
        #pragma unroll
        for (int m = 0; m < 4; ++m) {
          const float mx  = fmaxf(fmaxf(att[m][0], att[m][1]), fmaxf(att[m][2], att[m][3]));
          const float e0 = __expf(att[m][0] - mx);
          const float e1 = __expf(att[m][1] - mx);
          const float e2 = __expf(att[m][2] - mx);
          const float e3 = __expf(att[m][3] - mx);
          const float inv = __builtin_amdgcn_rcpf(e0 + e1 + e2 + e3);
          ctxv[u][t][m] = (e0 * acc[u][4 + t][0] + e1 * acc[u][4 + t][1] +
                           e2 * acc[u][4 + t][2] + e3 * acc[u][4 + t][3]) * inv;
        }
      }
    }

    // ---- P4: ctx -> LDS -> A-frag; out_proj (+residual via C-in); LN1 ----
    LDSFENCE;
    #pragma unroll
    for (int u = 0; u < 2; ++u)
      #pragma unroll
      for (int m = 0; m < 4; ++m) {
        cb[w][u][(g << 2) + m][c]      = ctxv[u][0][m];
        cb[w][u][(g << 2) + m][16 + c] = ctxv[u][1][m];
      }
    LDSFENCE;
    bf16x8 actx[2];
    #pragma unroll
    for (int u = 0; u < 2; ++u) actx[u] = fragA(&cb[w][u][c][0], kb);

    f32x4 yv[2][2];
    #pragma unroll
    for (int u = 0; u < 2; ++u) {
      #pragma unroll
      for (int t = 0; t < 2; ++t) {
        const bf16x8 bwo = ldfrag(wl, 6 + t);
        f32x4 cin;
        #pragma unroll
        for (int m = 0; m < 4; ++m) cin[m] = xcT[u][t][m] + bo[t];
        yv[u][t] = __builtin_amdgcn_mfma_f32_16x16x32_bf16(actx[u], bwo, cin, 0, 0, 0);
      }
    }
    float x1v[2][4][2];
    #pragma unroll
    for (int u = 0; u < 2; ++u) {
      #pragma unroll
      for (int m = 0; m < 4; ++m) {
        const float y0 = yv[u][0][m], y1 = yv[u][1][m];
        const float s  = red16(y0 + y1);
        const float ss = red16(fmaf(y0, y0, y1 * y1));
        const float mu  = s * 0.03125f;
        const float var = fmaf(ss, 0.03125f, -mu * mu);
        const float rs  = __builtin_amdgcn_rsqf(var + 1e-5f);
        x1v[u][m][0] = fmaf((y0 - mu), rs * l1s[0], l1b[0]);
        x1v[u][m][1] = fmaf((y1 - mu), rs * l1s[1], l1b[1]);
      }
    }

    // ---- P5: x1 -> LDS -> A-frag; FFN1 + relu ----
    LDSFENCE;
    #pragma unroll
    for (int u = 0; u < 2; ++u)
      #pragma unroll
      for (int m = 0; m < 4; ++m) {
        cb[w][u][(g << 2) + m][c]      = x1v[u][m][0];
        cb[w][u][(g << 2) + m][16 + c] = x1v[u][m][1];
      }
    LDSFENCE;
    float hv[2][4][2];
    #pragma unroll
    for (int u = 0; u < 2; ++u) {
      const bf16x8 ax1 = fragA(&cb[w][u][c][0], kb);
      #pragma unroll
      for (int t = 0; t < 2; ++t) {
        const bf16x8 bw1 = ldfrag(wl, 8 + t);
        f32x4 cin;
        #pragma unroll
        for (int m = 0; m < 4; ++m) cin[m] = bb1[t];
        const f32x4 hh = __builtin_amdgcn_mfma_f32_16x16x32_bf16(ax1, bw1, cin, 0, 0, 0);
        #pragma unroll
        for (int m = 0; m < 4; ++m) hv[u][m][t] = fmaxf(hh[m], 0.f);
      }
    }

    // ---- P6: h -> LDS -> A-frag; FFN2 (+residual via C-in); LN2 ----
    LDSFENCE;
    #pragma unroll
    for (int u = 0; u < 2; ++u)
      #pragma unroll
      for (int m = 0; m < 4; ++m) {
        cb[w][u][(g << 2) + m][c]      = hv[u][m][0];
        cb[w][u][(g << 2) + m][16 + c] = hv[u][m][1];
      }
    LDSFENCE;
    float x2v[2][4][2];
    #pragma unroll
    for (int u = 0; u < 2; ++u) {
      const bf16x8 ah2 = fragA(&cb[w][u][c][0], kb);
      f32x4 y2[2];
      #pragma unroll
      for (int t = 0; t < 2; ++t) {
        const bf16x8 bw2 = ldfrag(wl, 10 + t);
        f32x4 cin;
        #pragma unroll
        for (int m = 0; m < 4; ++m) cin[m] = x1v[u][m][t] + bb2[t];
        y2[t] = __builtin_amdgcn_mfma_f32_16x16x32_bf16(ah2, bw2, cin, 0, 0, 0);
      }
      #pragma unroll
      for (int m = 0; m < 4; ++m) {
        const float y0 = y2[0][m], y1 = y2[1][m];
        const float s  = red16(y0 + y1);
        const float ss = red16(fmaf(y0, y0, y1 * y1));
        const float mu  = s * 0.03125f;
        const float var = fmaf(ss, 0.03125f, -mu * mu);
        const float rs  = __builtin_amdgcn_rsqf(var + 1e-5f);
        x2v[u][m][0] = fmaf((y0 - mu), rs * l2s[0], l2b[0]);
        x2v[u][m][1] = fmaf((y1 - mu), rs * l2s[1], l2b[1]);
      }
    }

    // ---- P7: gated masked-softmax pooling + stores ----
    #pragma unroll
    for (int u = 0; u < 2; ++u) {
      float lg[4];
      #pragma unroll
      for (int m = 0; m < 4; ++m) {
        const float gp = red16(fmaf(x2v[u][m][0], gw[0], x2v[u][m][1] * gw[1]));
        lg[m] = (mskv[u][m] > 0.f) ? (gp + gb) : -1e9f;
      }
      const float mx = fmaxf(fmaxf(lg[0], lg[1]), fmaxf(lg[2], lg[3]));
      float em[4], se = 0.f, sem = 0.f;
      #pragma unroll
      for (int m = 0; m < 4; ++m) {
        const float e = __expf(lg[m] - mx);
        se += e;
        em[m] = e * mskv[u][m];
        sem += em[m];
      }
      const float invd = __builtin_amdgcn_rcpf(sem + 1e-8f * se);
      float wt[4];
      #pragma unroll
      for (int m = 0; m < 4; ++m) wt[m] = em[m] * invd;
      float f0 = 0.f, f1 = 0.f;
      #pragma unroll
      for (int m = 0; m < 4; ++m) {
        f0 = fmaf(x2v[u][m][0], wt[m], f0);
        f1 = fmaf(x2v[u][m][1], wt[m], f1);
      }
      float* orow = out + (size_t)(dr[u] + g) * 32;
      orow[c]      = f0;
      orow[16 + c] = f1;
      if (c == 0) {
        *reinterpret_cast<float4*>(out + (size_t)TLF_N * 32 + (size_t)(dr[u] + g) * 4) =
            make_float4(wt[0], wt[1], wt[2], wt[3]);
      }
    }
  }
}

extern "C" void kernel_launch(void* const* d_in, const int* in_sizes, int n_in,
                              void* d_out, int out_size, void* d_ws, size_t ws_size,
                              hipStream_t stream) {
  tlf_kernel<<<TLF_GRID, 256, 0, stream>>>(
      (const float*)d_in[0],  (const float*)d_in[1],  (const float*)d_in[2],
      (const float*)d_in[3],  (const float*)d_in[4],  (const float*)d_in[5],
      (const float*)d_in[6],  (const float*)d_in[7],  (const float*)d_in[8],
      (const float*)d_in[9],  (const float*)d_in[10], (const float*)d_in[11],
      (const float*)d_in[12], (const float*)d_in[13], (const float*)d_in[14],
      (const float*)d_in[15], (const float*)d_in[16], (float*)d_out);
}

// Round 4
// 162.663 us; speedup vs baseline: 2.3082x; 1.8217x over previous
//
#include <hip/hip_runtime.h>

#define TLF_N     500000
#define TLF_ITERS 10
#define TLF_GRID  12500  // 12500 blocks * 10 iters * 16 token-rows(=4 data rows) = 2M token-rows

typedef short bf16x8 __attribute__((ext_vector_type(8)));
typedef float f32x4  __attribute__((ext_vector_type(4)));
typedef int   i32x4  __attribute__((ext_vector_type(4)));

#define LDSFENCE asm volatile("s_waitcnt lgkmcnt(0)" ::: "memory")

__device__ __forceinline__ int cvt_pk(float lo, float hi) {
  int r;
  asm("v_cvt_pk_bf16_f32 %0, %1, %2" : "=v"(r) : "v"(lo), "v"(hi));
  return r;
}

__device__ __forceinline__ bf16x8 pack8f(float a0, float a1, float a2, float a3,
                                         float a4, float a5, float a6, float a7) {
  i32x4 r;
  r[0] = cvt_pk(a0, a1); r[1] = cvt_pk(a2, a3);
  r[2] = cvt_pk(a4, a5); r[3] = cvt_pk(a6, a7);
  return __builtin_bit_cast(bf16x8, r);
}

template<int CTRL>
__device__ __forceinline__ float dppf(float x) {
  return __builtin_bit_cast(float, __builtin_amdgcn_update_dpp(
      0, __builtin_bit_cast(int, x), CTRL, 0xF, 0xF, true));
}

// quad rotate by D: lane c receives value of lane (c&~3) | ((c+D)&3)
template<int D>
__device__ __forceinline__ float rot4(float x) {
  if constexpr (D == 0) return x;
  else if constexpr (D == 1) return dppf<0x39>(x);   // quad_perm [1,2,3,0]
  else if constexpr (D == 2) return dppf<0x4E>(x);   // quad_perm [2,3,0,1]
  else                       return dppf<0x93>(x);   // quad_perm [3,0,1,2]
}

__device__ __forceinline__ f32x4 ldc4(const float* p) {
  return *reinterpret_cast<const f32x4*>(p);
}

__launch_bounds__(64, 4)
__global__ void tlf_kernel(const float* __restrict__ tokens,
                           const float* __restrict__ amask,
                           const float* __restrict__ type_emb,
                           const float* __restrict__ ipw,
                           const float* __restrict__ ipb,
                           const float* __restrict__ opw,
                           const float* __restrict__ opb,
                           const float* __restrict__ l1sv,
                           const float* __restrict__ l1bv,
                           const float* __restrict__ w1,
                           const float* __restrict__ b1v,
                           const float* __restrict__ w2,
                           const float* __restrict__ b2v,
                           const float* __restrict__ l2sv,
                           const float* __restrict__ l2bv,
                           const float* __restrict__ gwv,
                           const float* __restrict__ gbv,
                           float* __restrict__ out) {
  // wave-uniform per-g constants (f32, broadcast reads):
  // slots (4 floats each): 0..5 qkv bias | 6,7 bo | 8,9 b1' | 10,11 b2+l1b
  //                        | 12,13 l1s | 14,15 l2s | 16,17 l2b | 18,19 gw
  __shared__ float cLDS[4 * 80];

  const int l  = threadIdx.x & 63;
  const int g  = l >> 4;           // k-subgroup / channel block
  const int c  = l & 15;           // column lane: token-row within tile
  const int g4 = g << 2;

  const float isq = 0.3535533905932738f;  // 1/sqrt(HD)

  // ---- weight A-frags (rows 16t+c, k-cols P(8g+j) = {4g+j} U {16+4g+j}) ----
  bf16x8 aw[6], ao[2], a1[2], a2[2];
  #pragma unroll
  for (int t = 0; t < 6; ++t) {
    const float s = (t < 2) ? isq : 1.0f;
    const float* r0 = ipw + (16 * t + c) * 32;
    const float4 wa = *(const float4*)(r0 + g4);
    const float4 wb = *(const float4*)(r0 + 16 + g4);
    aw[t] = pack8f(wa.x * s, wa.y * s, wa.z * s, wa.w * s,
                   wb.x * s, wb.y * s, wb.z * s, wb.w * s);
  }
  const float4 ls0 = *(const float4*)(l1sv + g4);
  const float4 ls1 = *(const float4*)(l1sv + 16 + g4);
  #pragma unroll
  for (int t = 0; t < 2; ++t) {
    const float* r0 = opw + (16 * t + c) * 32;
    const float* r1 = w1  + (16 * t + c) * 32;
    const float* r2 = w2  + (16 * t + c) * 32;
    float4 wa, wb;
    wa = *(const float4*)(r0 + g4); wb = *(const float4*)(r0 + 16 + g4);
    ao[t] = pack8f(wa.x, wa.y, wa.z, wa.w, wb.x, wb.y, wb.z, wb.w);
    wa = *(const float4*)(r1 + g4); wb = *(const float4*)(r1 + 16 + g4);
    a1[t] = pack8f(wa.x * ls0.x, wa.y * ls0.y, wa.z * ls0.z, wa.w * ls0.w,
                   wb.x * ls1.x, wb.y * ls1.y, wb.z * ls1.z, wb.w * ls1.w);
    wa = *(const float4*)(r2 + g4); wb = *(const float4*)(r2 + 16 + g4);
    a2[t] = pack8f(wa.x, wa.y, wa.z, wa.w, wb.x, wb.y, wb.z, wb.w);
  }

  // ---- per-g constants -> LDS (one lane per g computes) ----
  if (c == 0) {
    float* cp = cLDS + g * 80;
    #pragma unroll
    for (int t = 0; t < 6; ++t) {
      const float s = (t < 2) ? isq : 1.0f;
      #pragma unroll
      for (int m = 0; m < 4; ++m) cp[4 * t + m] = ipb[16 * t + g4 + m] * s;
    }
    #pragma unroll
    for (int t = 0; t < 2; ++t)
      #pragma unroll
      for (int m = 0; m < 4; ++m) {
        const int r = 16 * t + g4 + m;
        cp[24 + 4 * t + m] = opb[r];
        cp[40 + 4 * t + m] = b2v[r] + l1bv[r];
        cp[48 + 4 * t + m] = l1sv[r];
        cp[56 + 4 * t + m] = l2sv[r];
        cp[64 + 4 * t + m] = l2bv[r];
        cp[72 + 4 * t + m] = gwv[r];
      }
    // b1'[f2] = b1[f2] + sum_f l1b[f] * W1[f2][f]
    #pragma unroll
    for (int t = 0; t < 2; ++t)
      #pragma unroll
      for (int m = 0; m < 4; ++m) {
        const int r = 16 * t + g4 + m;
        float a = b1v[r];
        const float* wrow = w1 + r * 32;
        #pragma unroll
        for (int q8 = 0; q8 < 8; ++q8) {
          const float4 wv = *(const float4*)(wrow + q8 * 4);
          const float4 lb = *(const float4*)(l1bv + q8 * 4);
          a += wv.x * lb.x + wv.y * lb.y + wv.z * lb.z + wv.w * lb.w;
        }
        cp[32 + 4 * t + m] = a;
      }
  }
  LDSFENCE;

  // type_emb in B-frag layout: token m=c&3, channels P
  const float* tb = type_emb + (c & 3) * 32;
  const float4 te0 = *(const float4*)(tb + g4);
  const float4 te1 = *(const float4*)(tb + 16 + g4);
  const float gbs = gbv[0];

  const size_t tile0 = (size_t)blockIdx.x * TLF_ITERS;

  // prologue prefetch
  float4 nxa, nxb; float nmsk;
  {
    const float* tp = tokens + (tile0 * 16 + c) * 32;
    nxa = *(const float4*)(tp + g4);
    nxb = *(const float4*)(tp + 16 + g4);
    nmsk = amask[tile0 * 16 + c];
  }

  for (int it = 0; it < TLF_ITERS; ++it) {
    const size_t tile = tile0 + it;
    const float4 xa = nxa, xb = nxb;
    const float msk = nmsk;
    if (it + 1 < TLF_ITERS) {
      const float* tp = tokens + ((tile + 1) * 16 + c) * 32;
      nxa = *(const float4*)(tp + g4);
      nxb = *(const float4*)(tp + 16 + g4);
      nmsk = amask[(tile + 1) * 16 + c];
    }

    // LICM-defeating opaque offset for per-iter LDS const reads (32-bit, safe)
    int cgo = g * 80;
    asm volatile("" : "+v"(cgo));
    const float* cg = cLDS + cgo;

    // ---- x = tokens + te (f32, kept for exact residual) ----
    float x0[4] = {xa.x + te0.x, xa.y + te0.y, xa.z + te0.z, xa.w + te0.w};
    float x1[4] = {xb.x + te1.x, xb.y + te1.y, xb.z + te1.z, xb.w + te1.w};
    const bf16x8 bx = pack8f(x0[0], x0[1], x0[2], x0[3],
                             x1[0], x1[1], x1[2], x1[3]);

    // ---- Q, K (transposed outputs: lane(g,c) holds f=16t+4g+m, token c) ----
    f32x4 qa[2], ka[2];
    #pragma unroll
    for (int t = 0; t < 2; ++t)
      qa[t] = __builtin_amdgcn_mfma_f32_16x16x32_bf16(aw[t], bx, ldc4(cg + 4 * t), 0, 0, 0);
    #pragma unroll
    for (int t = 0; t < 2; ++t)
      ka[t] = __builtin_amdgcn_mfma_f32_16x16x32_bf16(aw[2 + t], bx, ldc4(cg + 8 + 4 * t), 0, 0, 0);

    // ---- scores + softmax (quad-DPP token rotations; xor16 joins head halves) ----
    const float bself = (msk > 0.f) ? 0.f : -1e9f;
    float wat[2][4];
    #pragma unroll
    for (int t = 0; t < 2; ++t) {
      float att[4];
#define TLF_SCORE(d)                                                        \
      { float p = qa[t][0] * rot4<d>(ka[t][0]);                             \
        p = fmaf(qa[t][1], rot4<d>(ka[t][1]), p);                           \
        p = fmaf(qa[t][2], rot4<d>(ka[t][2]), p);                           \
        p = fmaf(qa[t][3], rot4<d>(ka[t][3]), p);                           \
        p += __shfl_xor(p, 16, 64);                                         \
        att[d] = p + rot4<d>(bself); }
      TLF_SCORE(0) TLF_SCORE(1) TLF_SCORE(2) TLF_SCORE(3)
#undef TLF_SCORE
      const float mx = fmaxf(fmaxf(att[0], att[1]), fmaxf(att[2], att[3]));
      const float e0 = __expf(att[0] - mx);
      const float e1 = __expf(att[1] - mx);
      const float e2 = __expf(att[2] - mx);
      const float e3 = __expf(att[3] - mx);
      const float inv = __builtin_amdgcn_rcpf(e0 + e1 + e2 + e3);
      wat[t][0] = e0 * inv; wat[t][1] = e1 * inv;
      wat[t][2] = e2 * inv; wat[t][3] = e3 * inv;
    }

    // ---- V + PV (ctx stays transposed/in-lane) ----
    float ctx[2][4];
    #pragma unroll
    for (int t = 0; t < 2; ++t) {
      const f32x4 va = __builtin_amdgcn_mfma_f32_16x16x32_bf16(aw[4 + t], bx, ldc4(cg + 16 + 4 * t), 0, 0, 0);
#define TLF_PV(d)                                                           \
      { const float w_ = wat[t][d];                                         \
        ctx[t][0] = (d == 0) ? w_ * va[0] : fmaf(w_, rot4<d>(va[0]), ctx[t][0]); \
        ctx[t][1] = (d == 0) ? w_ * va[1] : fmaf(w_, rot4<d>(va[1]), ctx[t][1]); \
        ctx[t][2] = (d == 0) ? w_ * va[2] : fmaf(w_, rot4<d>(va[2]), ctx[t][2]); \
        ctx[t][3] = (d == 0) ? w_ * va[3] : fmaf(w_, rot4<d>(va[3]), ctx[t][3]); }
      TLF_PV(0) TLF_PV(1) TLF_PV(2) TLF_PV(3)
#undef TLF_PV
    }

    // ---- out_proj + exact-f32 residual via C-in; LN1 ----
    const bf16x8 bc = pack8f(ctx[0][0], ctx[0][1], ctx[0][2], ctx[0][3],
                             ctx[1][0], ctx[1][1], ctx[1][2], ctx[1][3]);
    f32x4 y[2];
    #pragma unroll
    for (int t = 0; t < 2; ++t) {
      f32x4 sd = ldc4(cg + 24 + 4 * t);
      #pragma unroll
      for (int m = 0; m < 4; ++m) sd[m] += (t == 0) ? x0[m] : x1[m];
      y[t] = __builtin_amdgcn_mfma_f32_16x16x32_bf16(ao[t], bc, sd, 0, 0, 0);
    }
    float s = 0.f, ss = 0.f;
    #pragma unroll
    for (int t = 0; t < 2; ++t)
      #pragma unroll
      for (int m = 0; m < 4; ++m) { s += y[t][m]; ss = fmaf(y[t][m], y[t][m], ss); }
    s  += __shfl_xor(s, 16, 64);  s  += __shfl_xor(s, 32, 64);
    ss += __shfl_xor(ss, 16, 64); ss += __shfl_xor(ss, 32, 64);
    {
      const float mu  = s * 0.03125f;
      const float var = fmaf(ss, 0.03125f, -mu * mu);
      const float rs  = __builtin_amdgcn_rsqf(var + 1e-5f);
      #pragma unroll
      for (int t = 0; t < 2; ++t)
        #pragma unroll
        for (int m = 0; m < 4; ++m) y[t][m] = (y[t][m] - mu) * rs;  // ynorm
    }

    // ---- FFN1 (W1 pre-scaled by l1s; bias = b1') ----
    const bf16x8 bn = pack8f(y[0][0], y[0][1], y[0][2], y[0][3],
                             y[1][0], y[1][1], y[1][2], y[1][3]);
    f32x4 h[2];
    #pragma unroll
    for (int t = 0; t < 2; ++t) {
      h[t] = __builtin_amdgcn_mfma_f32_16x16x32_bf16(a1[t], bn, ldc4(cg + 32 + 4 * t), 0, 0, 0);
      #pragma unroll
      for (int m = 0; m < 4; ++m) h[t][m] = fmaxf(h[t][m], 0.f);
    }

    // ---- FFN2 + residual (ynorm*l1s + b2+l1b via C-in); LN2 ----
    const bf16x8 bh = pack8f(h[0][0], h[0][1], h[0][2], h[0][3],
                             h[1][0], h[1][1], h[1][2], h[1][3]);
    f32x4 d2[2];
    #pragma unroll
    for (int t = 0; t < 2; ++t) {
      const f32x4 l1s4 = ldc4(cg + 48 + 4 * t);
      const f32x4 b2q  = ldc4(cg + 40 + 4 * t);
      f32x4 sd;
      #pragma unroll
      for (int m = 0; m < 4; ++m) sd[m] = fmaf(y[t][m], l1s4[m], b2q[m]);
      d2[t] = __builtin_amdgcn_mfma_f32_16x16x32_bf16(a2[t], bh, sd, 0, 0, 0);
    }
    float s2 = 0.f, ss2 = 0.f;
    #pragma unroll
    for (int t = 0; t < 2; ++t)
      #pragma unroll
      for (int m = 0; m < 4; ++m) { s2 += d2[t][m]; ss2 = fmaf(d2[t][m], d2[t][m], ss2); }
    s2  += __shfl_xor(s2, 16, 64);  s2  += __shfl_xor(s2, 32, 64);
    ss2 += __shfl_xor(ss2, 16, 64); ss2 += __shfl_xor(ss2, 32, 64);
    float x2[2][4];
    {
      const float mu  = s2 * 0.03125f;
      const float var = fmaf(ss2, 0.03125f, -mu * mu);
      const float rs  = __builtin_amdgcn_rsqf(var + 1e-5f);
      #pragma unroll
      for (int t = 0; t < 2; ++t) {
        const f32x4 l2s4 = ldc4(cg + 56 + 4 * t);
        const f32x4 l2b4 = ldc4(cg + 64 + 4 * t);
        #pragma unroll
        for (int m = 0; m < 4; ++m)
          x2[t][m] = fmaf((d2[t][m] - mu) * rs, l2s4[m], l2b4[m]);
      }
    }

    // ---- gated masked-softmax pooling (gate reduce + quad softmax) ----
    float gp = 0.f;
    #pragma unroll
    for (int t = 0; t < 2; ++t) {
      const f32x4 gw4 = ldc4(cg + 72 + 4 * t);
      #pragma unroll
      for (int m = 0; m < 4; ++m) gp = fmaf(x2[t][m], gw4[m], gp);
    }
    gp += __shfl_xor(gp, 16, 64); gp += __shfl_xor(gp, 32, 64);
    const float lg0 = (msk > 0.f) ? (gp + gbs) : -1e9f;
    const float lg1 = rot4<1>(lg0), lg2 = rot4<2>(lg0), lg3 = rot4<3>(lg0);
    const float mx  = fmaxf(fmaxf(lg0, lg1), fmaxf(lg2, lg3));
    const float e0 = __expf(lg0 - mx), e1 = __expf(lg1 - mx);
    const float e2 = __expf(lg2 - mx), e3 = __expf(lg3 - mx);
    const float m1 = rot4<1>(msk), m2 = rot4<2>(msk), m3 = rot4<3>(msk);
    const float em0 = e0 * msk, em1 = e1 * m1, em2 = e2 * m2, em3 = e3 * m3;
    const float se  = e0 + e1 + e2 + e3;
    const float invd = __builtin_amdgcn_rcpf((em0 + em1 + em2 + em3) + 1e-8f * se);
    const float wt0 = em0 * invd;  // own-token weight

    // fused[f] = quad-sum of wt_self * x2[f]
    float f8[2][4];
    #pragma unroll
    for (int t = 0; t < 2; ++t)
      #pragma unroll
      for (int m = 0; m < 4; ++m) {
        float v = x2[t][m] * wt0;
        v += dppf<0xB1>(v);
        v += dppf<0x4E>(v);
        f8[t][m] = v;
      }

    // ---- stores ----
    const int q = c >> 2, sl = c & 3;
    float* orow = out + (tile * 4 + q) * 32;
    if (sl == 0)
      *(float4*)(orow + g4) = make_float4(f8[0][0], f8[0][1], f8[0][2], f8[0][3]);
    if (sl == 1)
      *(float4*)(orow + 16 + g4) = make_float4(f8[1][0], f8[1][1], f8[1][2], f8[1][3]);
    if (sl == 2) {
      const float w0 = em0 * invd, w1_ = em1 * invd, w2_ = em2 * invd, w3_ = em3 * invd;
      // lane token = 2: tokens [0,1,2,3] are deltas [2,3,0,1]
      *(float4*)(out + (size_t)TLF_N * 32 + (tile * 4 + q) * 4) =
          make_float4(w2_, w3_, w0, w1_);
    }
  }
}

extern "C" void kernel_launch(void* const* d_in, const int* in_sizes, int n_in,
                              void* d_out, int out_size, void* d_ws, size_t ws_size,
                              hipStream_t stream) {
  tlf_kernel<<<TLF_GRID, 64, 0, stream>>>(
      (const float*)d_in[0],  (const float*)d_in[1],  (const float*)d_in[2],
      (const float*)d_in[3],  (const float*)d_in[4],  (const float*)d_in[5],
      (const float*)d_in[6],  (const float*)d_in[7],  (const float*)d_in[8],
      (const float*)d_in[9],  (const float*)d_in[10], (const float*)d_in[11],
      (const float*)d_in[12], (const float*)d_in[13], (const float*)d_in[14],
      (const float*)d_in[15], (const float*)d_in[16], (float*)d_out);
}